// Round 5
// baseline (694.652 us; speedup 1.0000x reference)
//
#include <hip/hip_runtime.h>
#include <hip/hip_cooperative_groups.h>

namespace cg = cooperative_groups;

// DeepFM: B=16384, D=1024, L=4.
// Primary: ONE cooperative kernel (512 blocks x 256 threads): phase-0 converts
// Ws/Wo->bf16 and x->bf16(+rowsum), then 5 GEMM layers with grid.sync between.
// GEMM body = round-3 verified structure: 128x128 tile, BK=64 (2x 32-wide LDS
// buffers), global_load_lds w=16, 16x16x32 bf16 MFMA, 2x2 waves, acc 4x4.
// Fallback: if cooperative launch is rejected, run the round-3 split kernels.

#define DDIM 1024
#define BROWS 16384

typedef __attribute__((ext_vector_type(8))) short s8v;   // 8 bf16
typedef __attribute__((ext_vector_type(4))) float f4v;   // 4 fp32

__device__ __forceinline__ unsigned short f2bf(float f) {
    unsigned int u = __float_as_uint(f);
    u += 0x7fffu + ((u >> 16) & 1u);   // round-to-nearest-even
    return (unsigned short)(u >> 16);
}
__device__ __forceinline__ float bf2f(unsigned short u) {
    return __uint_as_float(((unsigned int)u) << 16);
}
__device__ __forceinline__ void gld16(const void* g, void* l) {
    __builtin_amdgcn_global_load_lds(
        (const __attribute__((address_space(1))) unsigned int*)g,
        (__attribute__((address_space(3))) unsigned int*)l, 16, 0, 0);
}

// ======================= cooperative fused kernel ========================
__global__ __launch_bounds__(256, 3) void fused_coop(
    const float* __restrict__ x,  const float* __restrict__ Ws,
    const float* __restrict__ bs, const float* __restrict__ Wo,
    const float* __restrict__ bo, float* __restrict__ out,
    unsigned short* __restrict__ xb, unsigned short* __restrict__ h0,
    unsigned short* __restrict__ h1, unsigned short* __restrict__ wb,
    float* __restrict__ rsm)
{
    // 4 x 8KB staging: [0]=A k-lo [1]=A k-hi [2]=B k-lo [3]=B k-hi.
    // Reused as 32KB C tile in epilogues.
    __shared__ unsigned short smem[4][128 * 32];

    const int t = threadIdx.x;
    const int lane = t & 63, wave = t >> 6;

    // ---------------- phase 0: convert weights + x ----------------
    {
        const int gid = blockIdx.x * 256 + t;            // 0..131071
        #pragma unroll
        for (int j = 0; j < 10; ++j) {                   // 1310720 float4 total
            const int idx = gid + j * 131072;
            const float4 v = (idx < 1048576) ? ((const float4*)Ws)[idx]
                                             : ((const float4*)Wo)[idx - 1048576];
            ushort4 o;
            o.x = f2bf(v.x); o.y = f2bf(v.y); o.z = f2bf(v.z); o.w = f2bf(v.w);
            ((ushort4*)wb)[idx] = o;
        }
        // x: 32 rows per block, 8 per wave
        #pragma unroll 1
        for (int j = 0; j < 8; ++j) {
            const int row = blockIdx.x * 32 + wave * 8 + j;
            const float* xr = x + (size_t)row * DDIM;
            float s = 0.f;
            #pragma unroll
            for (int it = 0; it < 4; ++it) {
                const int col = it * 256 + lane * 4;
                const float4 v = *(const float4*)(xr + col);
                s += v.x + v.y + v.z + v.w;
                ushort4 o;
                o.x = f2bf(v.x); o.y = f2bf(v.y); o.z = f2bf(v.z); o.w = f2bf(v.w);
                *(ushort4*)(xb + (size_t)row * DDIM + col) = o;
            }
            #pragma unroll
            for (int off = 32; off; off >>= 1) s += __shfl_down(s, off);
            if (lane == 0) rsm[row] = s;
        }
    }
    cg::this_grid().sync();

    const unsigned short* hin[5] = {xb, h0, h1, h0, h1};
    unsigned short* hout[4] = {h0, h1, h0, h1};

    const int wm = wave & 1, wn = wave >> 1;   // 2x2 wave grid of 64x64
    const int mrow = lane & 15;
    const int quad = lane >> 4;
    const int koff = quad * 8;
    const int c0r = t >> 2, c0k = (t & 3) * 8; // staging row/k-chunk

    #pragma unroll 1
    for (int l = 0; l < 5; ++l) {
        const unsigned short* A = hin[l];
        const unsigned short* W = wb + (size_t)l * DDIM * DDIM;
        const float* bias = (l < 4) ? bs + l * DDIM : bo;

        #pragma unroll 1
        for (int tt = 0; tt < 2; ++tt) {
            const int tile = blockIdx.x * 2 + tt;        // both tiles same row-slab
            const int rowBase = (tile >> 3) * 128;
            const int colBase = (tile & 7) * 128;

            f4v acc[4][4] = {};

            #pragma unroll 1
            for (int kt = 0; kt < DDIM; kt += 64) {
                __syncthreads();
                const unsigned short* a0 = A + (size_t)(rowBase + c0r) * DDIM + kt + c0k;
                const unsigned short* b0 = W + (size_t)(colBase + c0r) * DDIM + kt + c0k;
                gld16(a0,                  (char*)smem[0] + t * 16);
                gld16(a0 + 64 * DDIM,      (char*)smem[0] + (t + 256) * 16);
                gld16(b0,                  (char*)smem[2] + t * 16);
                gld16(b0 + 64 * DDIM,      (char*)smem[2] + (t + 256) * 16);
                gld16(a0 + 32,             (char*)smem[1] + t * 16);
                gld16(a0 + 64 * DDIM + 32, (char*)smem[1] + (t + 256) * 16);
                gld16(b0 + 32,             (char*)smem[3] + t * 16);
                gld16(b0 + 64 * DDIM + 32, (char*)smem[3] + (t + 256) * 16);
                __syncthreads();
                #pragma unroll
                for (int s = 0; s < 2; ++s) {
                    s8v af[4], bfr[4];
                    #pragma unroll
                    for (int mi = 0; mi < 4; ++mi)
                        af[mi] = *(const s8v*)&smem[s][(wm * 64 + mi * 16 + mrow) * 32 + koff];
                    #pragma unroll
                    for (int ni = 0; ni < 4; ++ni)
                        bfr[ni] = *(const s8v*)&smem[2 + s][(wn * 64 + ni * 16 + mrow) * 32 + koff];
                    #pragma unroll
                    for (int mi = 0; mi < 4; ++mi)
                        #pragma unroll
                        for (int ni = 0; ni < 4; ++ni)
                            acc[mi][ni] = __builtin_amdgcn_mfma_f32_16x16x32_bf16(
                                af[mi], bfr[ni], acc[mi][ni], 0, 0, 0);
                }
            }

            // C/D layout: col = lane&15, row = quad*4 + reg  (m89/m91)
            if (l < 4) {
                __syncthreads();
                unsigned short* sC = (unsigned short*)smem;   // 128x128 bf16
                #pragma unroll
                for (int ni = 0; ni < 4; ++ni) {
                    const int n = wn * 64 + ni * 16 + mrow;
                    const float bv = bias[colBase + n];
                    #pragma unroll
                    for (int mi = 0; mi < 4; ++mi)
                        #pragma unroll
                        for (int r = 0; r < 4; ++r) {
                            const int row = wm * 64 + mi * 16 + quad * 4 + r;
                            float v = acc[mi][ni][r] + bv;
                            v = v > 0.f ? v : 0.f;
                            sC[row * 128 + n] = f2bf(v);
                        }
                }
                __syncthreads();
                unsigned short* o16 = hout[l];
                #pragma unroll
                for (int i = 0; i < 8; ++i) {
                    const int idx = t + i * 256;              // ushort8 chunk 0..2047
                    const int row = idx >> 4, ch = idx & 15;
                    s8v c = *(const s8v*)&sC[row * 128 + ch * 8];
                    if (l == 3) {
                        const float rsv = rsm[rowBase + row];
                        const s8v xv = *(const s8v*)&xb[(size_t)(rowBase + row) * DDIM + colBase + ch * 8];
                        #pragma unroll
                        for (int j = 0; j < 8; ++j) {
                            float it = bf2f((unsigned short)xv[j]) * rsv;
                            it = it > 0.f ? it : 0.f;
                            c[j] = (short)f2bf(0.5f * (bf2f((unsigned short)c[j]) + it));
                        }
                    }
                    *(s8v*)&o16[(size_t)(rowBase + row) * DDIM + colBase + ch * 8] = c;
                }
            } else {
                float* sCf = (float*)smem;                    // 64x128 fp32 = 32 KB
                #pragma unroll 1
                for (int half = 0; half < 2; ++half) {
                    __syncthreads();
                    if (wm == half) {
                        #pragma unroll
                        for (int ni = 0; ni < 4; ++ni) {
                            const int n = wn * 64 + ni * 16 + mrow;
                            const float bv = bias[colBase + n];
                            #pragma unroll
                            for (int mi = 0; mi < 4; ++mi)
                                #pragma unroll
                                for (int r = 0; r < 4; ++r)
                                    sCf[(mi * 16 + quad * 4 + r) * 128 + n] = acc[mi][ni][r] + bv;
                        }
                    }
                    __syncthreads();
                    #pragma unroll
                    for (int i = 0; i < 8; ++i) {
                        const int idx = t + i * 256;          // float4 chunk 0..2047
                        const int row = idx >> 5, ch = idx & 31;
                        const float4 v = ((const float4*)sCf)[idx];
                        ((float4*)(out + (size_t)(rowBase + half * 64 + row) * DDIM + colBase))[ch] = v;
                    }
                }
            }
        }
        if (l < 4) cg::this_grid().sync();
    }
}

// ======================= fallback split kernels ==========================
__global__ __launch_bounds__(256) void prep_kernel(
    const float* __restrict__ x, unsigned short* __restrict__ xb,
    float* __restrict__ rowsum)
{
    const int row = blockIdx.x;
    const int t = threadIdx.x;
    const float4 v = *(const float4*)(x + (size_t)row * DDIM + t * 4);
    ushort4 o;
    o.x = f2bf(v.x); o.y = f2bf(v.y); o.z = f2bf(v.z); o.w = f2bf(v.w);
    *(ushort4*)(xb + (size_t)row * DDIM + t * 4) = o;
    float s = v.x + v.y + v.z + v.w;
    #pragma unroll
    for (int off = 32; off > 0; off >>= 1) s += __shfl_down(s, off, 64);
    __shared__ float red[4];
    const int wave = t >> 6, lane = t & 63;
    if (lane == 0) red[wave] = s;
    __syncthreads();
    if (t == 0) rowsum[row] = red[0] + red[1] + red[2] + red[3];
}

__global__ __launch_bounds__(256) void cvt_kernel(
    const float* __restrict__ Ws, const float* __restrict__ Wo,
    unsigned short* __restrict__ out)
{
    const int i = (blockIdx.x * 256 + threadIdx.x) * 4;
    const float* src = (i < 4 * DDIM * DDIM) ? (Ws + i) : (Wo + (i - 4 * DDIM * DDIM));
    const float4 v = *(const float4*)src;
    ushort4 o;
    o.x = f2bf(v.x); o.y = f2bf(v.y); o.z = f2bf(v.z); o.w = f2bf(v.w);
    *(ushort4*)(out + i) = o;
}

template <int MODE>
__global__ __launch_bounds__(256, 2) void gemm_bt(
    const unsigned short* __restrict__ A,
    const unsigned short* __restrict__ Bw,
    const float* __restrict__ bias,
    void* __restrict__ out,
    const unsigned short* __restrict__ xb,
    const float* __restrict__ rowsum)
{
    constexpr int K = DDIM, N = DDIM;
    __shared__ unsigned short smem[4][128 * 32];

    const int t = threadIdx.x;
    const int wave = t >> 6, lane = t & 63;
    const int wm = wave & 1, wn = wave >> 1;
    const int rowBase = blockIdx.x * 128;
    const int colBase = blockIdx.y * 128;

    f4v acc[4][4] = {};
    const int c0r = t >> 2, c0k = (t & 3) * 8;
    const int mrow = lane & 15;
    const int koff = (lane >> 4) * 8;

    for (int kt = 0; kt < K; kt += 64) {
        if (kt) __syncthreads();
        const unsigned short* a0 = A  + (size_t)(rowBase + c0r) * K + kt + c0k;
        const unsigned short* b0 = Bw + (size_t)(colBase + c0r) * K + kt + c0k;
        gld16(a0,               (char*)smem[0] + t * 16);
        gld16(a0 + 64 * K,      (char*)smem[0] + (t + 256) * 16);
        gld16(b0,               (char*)smem[2] + t * 16);
        gld16(b0 + 64 * K,      (char*)smem[2] + (t + 256) * 16);
        gld16(a0 + 32,          (char*)smem[1] + t * 16);
        gld16(a0 + 64 * K + 32, (char*)smem[1] + (t + 256) * 16);
        gld16(b0 + 32,          (char*)smem[3] + t * 16);
        gld16(b0 + 64 * K + 32, (char*)smem[3] + (t + 256) * 16);
        __syncthreads();
        #pragma unroll
        for (int s = 0; s < 2; ++s) {
            s8v af[4], bfr[4];
            #pragma unroll
            for (int mi = 0; mi < 4; ++mi)
                af[mi] = *(const s8v*)&smem[s][(wm * 64 + mi * 16 + mrow) * 32 + koff];
            #pragma unroll
            for (int ni = 0; ni < 4; ++ni)
                bfr[ni] = *(const s8v*)&smem[2 + s][(wn * 64 + ni * 16 + mrow) * 32 + koff];
            #pragma unroll
            for (int mi = 0; mi < 4; ++mi)
                #pragma unroll
                for (int ni = 0; ni < 4; ++ni)
                    acc[mi][ni] = __builtin_amdgcn_mfma_f32_16x16x32_bf16(
                        af[mi], bfr[ni], acc[mi][ni], 0, 0, 0);
        }
    }

    const int quad = lane >> 4;
    if (MODE == 2) {
        float* o = (float*)out;
        #pragma unroll
        for (int ni = 0; ni < 4; ++ni) {
            const int n = colBase + wn * 64 + ni * 16 + mrow;
            const float bv = bias[n];
            #pragma unroll
            for (int mi = 0; mi < 4; ++mi)
                #pragma unroll
                for (int r = 0; r < 4; ++r) {
                    const int row = rowBase + wm * 64 + mi * 16 + quad * 4 + r;
                    o[(size_t)row * N + n] = acc[mi][ni][r] + bv;
                }
        }
    } else {
        __syncthreads();
        unsigned short* sC = (unsigned short*)smem;
        #pragma unroll
        for (int ni = 0; ni < 4; ++ni) {
            const int n = wn * 64 + ni * 16 + mrow;
            const float bv = bias[colBase + n];
            #pragma unroll
            for (int mi = 0; mi < 4; ++mi)
                #pragma unroll
                for (int r = 0; r < 4; ++r) {
                    const int row = wm * 64 + mi * 16 + quad * 4 + r;
                    float v = acc[mi][ni][r] + bv;
                    v = v > 0.f ? v : 0.f;
                    sC[row * 128 + n] = f2bf(v);
                }
        }
        __syncthreads();
        unsigned short* o16 = (unsigned short*)out;
        #pragma unroll
        for (int i = 0; i < 8; ++i) {
            const int idx = t + i * 256;
            const int row = idx >> 4, ch = idx & 15;
            s8v c = *(const s8v*)&sC[row * 128 + ch * 8];
            if (MODE == 1) {
                const float rsv = rowsum[rowBase + row];
                const s8v xv = *(const s8v*)&xb[(size_t)(rowBase + row) * DDIM + colBase + ch * 8];
                #pragma unroll
                for (int j = 0; j < 8; ++j) {
                    float it = bf2f((unsigned short)xv[j]) * rsv;
                    it = it > 0.f ? it : 0.f;
                    c[j] = (short)f2bf(0.5f * (bf2f((unsigned short)c[j]) + it));
                }
            }
            *(s8v*)&o16[(size_t)(rowBase + row) * DDIM + colBase + ch * 8] = c;
        }
    }
}

extern "C" void kernel_launch(void* const* d_in, const int* in_sizes, int n_in,
                              void* d_out, int out_size, void* d_ws, size_t ws_size,
                              hipStream_t stream) {
    const float* x  = (const float*)d_in[0];
    const float* Ws = (const float*)d_in[1];
    const float* bs = (const float*)d_in[2];
    const float* Wo = (const float*)d_in[3];
    const float* bo = (const float*)d_in[4];
    float* out = (float*)d_out;

    char* ws = (char*)d_ws;
    unsigned short* xb  = (unsigned short*)(ws);                  // 32 MB
    unsigned short* h0  = (unsigned short*)(ws + 33554432);       // 32 MB
    unsigned short* h1  = (unsigned short*)(ws + 67108864);       // 32 MB
    unsigned short* wb  = (unsigned short*)(ws + 100663296);      // 10 MB
    float*          rsm = (float*)(ws + 111149056);               // 64 KB

    void* args[] = {&x, &Ws, &bs, &Wo, &bo, &out, &xb, &h0, &h1, &wb, &rsm};
    hipError_t e = hipLaunchCooperativeKernel((const void*)fused_coop,
                                              dim3(512), dim3(256), args, 0, stream);
    if (e != hipSuccess) {
        // fallback: proven split-kernel chain
        prep_kernel<<<BROWS, 256, 0, stream>>>(x, xb, rsm);
        cvt_kernel<<<(5 * DDIM * DDIM) / 1024, 256, 0, stream>>>(Ws, Wo, wb);
        const size_t WSZ = (size_t)DDIM * DDIM;
        dim3 g(BROWS / 128, DDIM / 128);
        gemm_bt<0><<<g, 256, 0, stream>>>(xb, wb,           bs,            h0, nullptr, nullptr);
        gemm_bt<0><<<g, 256, 0, stream>>>(h0, wb + 1 * WSZ, bs + 1 * DDIM, h1, nullptr, nullptr);
        gemm_bt<0><<<g, 256, 0, stream>>>(h1, wb + 2 * WSZ, bs + 2 * DDIM, h0, nullptr, nullptr);
        gemm_bt<1><<<g, 256, 0, stream>>>(h0, wb + 3 * WSZ, bs + 3 * DDIM, h1, xb, rsm);
        gemm_bt<2><<<g, 256, 0, stream>>>(h1, wb + 4 * WSZ, bo,            out, nullptr, nullptr);
    }
}

// Round 6
// 366.981 us; speedup vs baseline: 1.8929x; 1.8929x over previous
//
#include <hip/hip_runtime.h>

// DeepFM: B=16384, D=1024, L=4. Split-GEMM chain (round-3 structure) with:
//  - __launch_bounds__(256,3): 3 blocks/CU (VGPR 68 + AGPR 64 = 132 <= 170)
//  - prep (x->bf16 + rowsum) and weight cvt fused into ONE kernel
//  - MODE-2 (fp32 final) epilogue routed through LDS for full-line stores

#define DDIM 1024
#define BROWS 16384

typedef __attribute__((ext_vector_type(8))) short s8v;   // 8 bf16
typedef __attribute__((ext_vector_type(4))) float f4v;   // 4 fp32

__device__ __forceinline__ unsigned short f2bf(float f) {
    unsigned int u = __float_as_uint(f);
    u += 0x7fffu + ((u >> 16) & 1u);   // round-to-nearest-even
    return (unsigned short)(u >> 16);
}
__device__ __forceinline__ float bf2f(unsigned short u) {
    return __uint_as_float(((unsigned int)u) << 16);
}
__device__ __forceinline__ void gld16(const void* g, void* l) {
    __builtin_amdgcn_global_load_lds(
        (const __attribute__((address_space(1))) unsigned int*)g,
        (__attribute__((address_space(3))) unsigned int*)l, 16, 0, 0);
}

// -------- fused prep: blocks [0,16384) x rows; [16384, 17664) weights ----
__global__ __launch_bounds__(256) void prep_cvt_kernel(
    const float* __restrict__ x,  const float* __restrict__ Ws,
    const float* __restrict__ Wo, unsigned short* __restrict__ xb,
    unsigned short* __restrict__ wb, float* __restrict__ rowsum)
{
    const int t = threadIdx.x;
    if (blockIdx.x < BROWS) {
        const int row = blockIdx.x;
        const float4 v = *(const float4*)(x + (size_t)row * DDIM + t * 4);
        ushort4 o;
        o.x = f2bf(v.x); o.y = f2bf(v.y); o.z = f2bf(v.z); o.w = f2bf(v.w);
        *(ushort4*)(xb + (size_t)row * DDIM + t * 4) = o;
        float s = v.x + v.y + v.z + v.w;
        #pragma unroll
        for (int off = 32; off > 0; off >>= 1) s += __shfl_down(s, off, 64);
        __shared__ float red[4];
        const int wave = t >> 6, lane = t & 63;
        if (lane == 0) red[wave] = s;
        __syncthreads();
        if (t == 0) rowsum[row] = red[0] + red[1] + red[2] + red[3];
    } else {
        // 5*1024*1024 floats = 1,310,720 float4; 1280 blocks x 1024 float4
        const int base = (blockIdx.x - BROWS) * 1024;
        #pragma unroll
        for (int j = 0; j < 4; ++j) {
            const int idx = base + j * 256 + t;
            const float4 v = (idx < 4 * 262144) ? ((const float4*)Ws)[idx]
                                                : ((const float4*)Wo)[idx - 4 * 262144];
            ushort4 o;
            o.x = f2bf(v.x); o.y = f2bf(v.y); o.z = f2bf(v.z); o.w = f2bf(v.w);
            ((ushort4*)wb)[idx] = o;
        }
    }
}

// ---------------- GEMM: C = A(MxK) @ Bw(NxK)^T + bias --------------------
// MODE 0: out bf16 = relu(z)
// MODE 1: out bf16 = 0.5*(relu(z) + relu(xb*rowsum))   (layer 4 fusion)
// MODE 2: out fp32 = z                                  (final layer)
template <int MODE>
__global__ __launch_bounds__(256, 3) void gemm_bt(
    const unsigned short* __restrict__ A,
    const unsigned short* __restrict__ Bw,
    const float* __restrict__ bias,
    void* __restrict__ out,
    const unsigned short* __restrict__ xb,
    const float* __restrict__ rowsum)
{
    constexpr int K = DDIM, N = DDIM;
    // 4 x 8KB staging: [0]=A k-lo [1]=A k-hi [2]=B k-lo [3]=B k-hi.
    // Reused as 32KB C tile in epilogues.
    __shared__ unsigned short smem[4][128 * 32];

    const int t = threadIdx.x;
    const int wave = t >> 6, lane = t & 63;
    const int wm = wave & 1, wn = wave >> 1;       // 2x2 wave grid of 64x64
    const int rowBase = blockIdx.x * 128;
    const int colBase = blockIdx.y * 128;

    f4v acc[4][4] = {};
    const int c0r = t >> 2, c0k = (t & 3) * 8;
    const int mrow = lane & 15;
    const int quad = lane >> 4;
    const int koff = quad * 8;

    for (int kt = 0; kt < K; kt += 64) {
        if (kt) __syncthreads();
        const unsigned short* a0 = A  + (size_t)(rowBase + c0r) * K + kt + c0k;
        const unsigned short* b0 = Bw + (size_t)(colBase + c0r) * K + kt + c0k;
        gld16(a0,               (char*)smem[0] + t * 16);
        gld16(a0 + 64 * K,      (char*)smem[0] + (t + 256) * 16);
        gld16(b0,               (char*)smem[2] + t * 16);
        gld16(b0 + 64 * K,      (char*)smem[2] + (t + 256) * 16);
        gld16(a0 + 32,          (char*)smem[1] + t * 16);
        gld16(a0 + 64 * K + 32, (char*)smem[1] + (t + 256) * 16);
        gld16(b0 + 32,          (char*)smem[3] + t * 16);
        gld16(b0 + 64 * K + 32, (char*)smem[3] + (t + 256) * 16);
        __syncthreads();
        #pragma unroll
        for (int s = 0; s < 2; ++s) {
            s8v af[4], bfr[4];
            #pragma unroll
            for (int mi = 0; mi < 4; ++mi)
                af[mi] = *(const s8v*)&smem[s][(wm * 64 + mi * 16 + mrow) * 32 + koff];
            #pragma unroll
            for (int ni = 0; ni < 4; ++ni)
                bfr[ni] = *(const s8v*)&smem[2 + s][(wn * 64 + ni * 16 + mrow) * 32 + koff];
            #pragma unroll
            for (int mi = 0; mi < 4; ++mi)
                #pragma unroll
                for (int ni = 0; ni < 4; ++ni)
                    acc[mi][ni] = __builtin_amdgcn_mfma_f32_16x16x32_bf16(
                        af[mi], bfr[ni], acc[mi][ni], 0, 0, 0);
        }
    }

    // Epilogue. C/D layout: col = lane&15, row = quad*4 + reg  (m89/m91)
    if (MODE == 2) {
        float* sCf = (float*)smem;                    // 64x128 fp32 = 32 KB
        float* o = (float*)out;
        #pragma unroll 1
        for (int half = 0; half < 2; ++half) {
            __syncthreads();
            if (wm == half) {
                #pragma unroll
                for (int ni = 0; ni < 4; ++ni) {
                    const int n = wn * 64 + ni * 16 + mrow;
                    const float bv = bias[colBase + n];
                    #pragma unroll
                    for (int mi = 0; mi < 4; ++mi)
                        #pragma unroll
                        for (int r = 0; r < 4; ++r)
                            sCf[(mi * 16 + quad * 4 + r) * 128 + n] = acc[mi][ni][r] + bv;
                }
            }
            __syncthreads();
            #pragma unroll
            for (int i = 0; i < 8; ++i) {
                const int idx = t + i * 256;          // float4 chunk 0..2047
                const int row = idx >> 5, ch = idx & 31;
                const float4 v = ((const float4*)sCf)[idx];
                ((float4*)(o + (size_t)(rowBase + half * 64 + row) * N + colBase))[ch] = v;
            }
        }
    } else {
        __syncthreads();
        unsigned short* sC = (unsigned short*)smem;   // 128x128 bf16
        #pragma unroll
        for (int ni = 0; ni < 4; ++ni) {
            const int n = wn * 64 + ni * 16 + mrow;
            const float bv = bias[colBase + n];
            #pragma unroll
            for (int mi = 0; mi < 4; ++mi)
                #pragma unroll
                for (int r = 0; r < 4; ++r) {
                    const int row = wm * 64 + mi * 16 + quad * 4 + r;
                    float v = acc[mi][ni][r] + bv;
                    v = v > 0.f ? v : 0.f;
                    sC[row * 128 + n] = f2bf(v);
                }
        }
        __syncthreads();
        unsigned short* o16 = (unsigned short*)out;
        #pragma unroll
        for (int i = 0; i < 8; ++i) {
            const int idx = t + i * 256;              // ushort8 chunk 0..2047
            const int row = idx >> 4, ch = idx & 15;
            s8v c = *(const s8v*)&sC[row * 128 + ch * 8];
            if (MODE == 1) {
                const float rsv = rowsum[rowBase + row];
                const s8v xv = *(const s8v*)&xb[(size_t)(rowBase + row) * DDIM + colBase + ch * 8];
                #pragma unroll
                for (int j = 0; j < 8; ++j) {
                    float it = bf2f((unsigned short)xv[j]) * rsv;
                    it = it > 0.f ? it : 0.f;
                    c[j] = (short)f2bf(0.5f * (bf2f((unsigned short)c[j]) + it));
                }
            }
            *(s8v*)&o16[(size_t)(rowBase + row) * DDIM + colBase + ch * 8] = c;
        }
    }
}

extern "C" void kernel_launch(void* const* d_in, const int* in_sizes, int n_in,
                              void* d_out, int out_size, void* d_ws, size_t ws_size,
                              hipStream_t stream) {
    const float* x  = (const float*)d_in[0];
    const float* Ws = (const float*)d_in[1];
    const float* bs = (const float*)d_in[2];
    const float* Wo = (const float*)d_in[3];
    const float* bo = (const float*)d_in[4];
    float* out = (float*)d_out;

    char* ws = (char*)d_ws;
    unsigned short* xb  = (unsigned short*)(ws);                 // 32 MB bf16 x
    unsigned short* h0  = (unsigned short*)(ws + 33554432);      // 32 MB
    unsigned short* h1  = (unsigned short*)(ws + 67108864);      // 32 MB
    unsigned short* wb  = (unsigned short*)(ws + 100663296);     // 10 MB weights bf16
    float*          rsm = (float*)(ws + 111149056);              // 64 KB rowsum

    prep_cvt_kernel<<<BROWS + 1280, 256, 0, stream>>>(x, Ws, Wo, xb, wb, rsm);

    const size_t WSZ = (size_t)DDIM * DDIM;
    dim3 g(BROWS / 128, DDIM / 128);
    gemm_bt<0><<<g, 256, 0, stream>>>(xb, wb,           bs,            h0, nullptr, nullptr);
    gemm_bt<0><<<g, 256, 0, stream>>>(h0, wb + 1 * WSZ, bs + 1 * DDIM, h1, nullptr, nullptr);
    gemm_bt<0><<<g, 256, 0, stream>>>(h1, wb + 2 * WSZ, bs + 2 * DDIM, h0, nullptr, nullptr);
    gemm_bt<1><<<g, 256, 0, stream>>>(h0, wb + 3 * WSZ, bs + 3 * DDIM, h1, xb, rsm);
    gemm_bt<2><<<g, 256, 0, stream>>>(h1, wb + 4 * WSZ, bo,            out, nullptr, nullptr);
}